// Round 6
// baseline (45.037 us; speedup 1.0000x reference)
//
#include <hip/hip_runtime.h>
#include <math.h>

// B=64, C=3, H=W=256 fixed by the reference problem.
#define BATCH 64
#define CH 3
#define IMH 256
#define IMW 256
#define HW (IMH * IMW)
#define NXCD 8

// 64x32 output tile, double-buffered channel pipeline.
// Row-span bound: |id_|max*63 + ie_max*31 + 3 = 0.7885*63 + 1.2267*31 + 3 < 92.
#define NRMAX 92
#define XW 68          // staged cols: 63*c + hi-tap + align slack + 1 <= 68
#define XW4 17         // float4 per staged row
#define LDSF (NRMAX * XW)
#define NPF 7          // prefetch regs: ceil(NRMAX*XW4/256) = ceil(1564/256)

__device__ __forceinline__ int clampi(int v, int lo, int hi) {
    return min(max(v, lo), hi);
}

__global__ __launch_bounds__(256, 3) void TCR_52536039964687_warp(
    const float* __restrict__ img,
    const float* __restrict__ rnd,
    float* __restrict__ out) {
    __shared__ float bufA[LDSF];
    __shared__ float bufB[LDSF];

    // 2048 blocks = 64 images x 32 tiles (4x in x, 8x in y of 64x32).
    // XCD-affinity swizzle: all 32 tiles of image b land on XCD b%8.
    int w = blockIdx.x;
    int xcd = w & (NXCD - 1);
    int t = w >> 3;                  // 0..255 within XCD
    int b = ((t >> 5) << 3) | xcd;   // image index
    int tile = t & 31;
    int X0 = (tile & 3) << 6;        // tile col origin (64-wide)
    int Y0 = (tile >> 2) << 5;       // tile row origin (32-tall)

    int tid = threadIdx.x;
    int dx = tid & 63;               // output col within tile
    int qy = tid >> 6;               // 0..3 row phase; rows Y0+qy+4k, k<8

    // ---- per-image inverse affine coefficients (simplified; a==0 exactly) ----
    const float r = rnd[b];
    const float ANG  = 0.34906585039886590f;   // deg2rad(20)
    const float ANG2 = 0.69813170079773179f;   // 2*ANG
    const float Wc = (float)IMH;
    const float Hc = (float)IMW;

    float tx  = 12.0f * r - 6.0f;
    float ty  = tx;
    float rho = ANG2 * r - ANG;

    float s = __sinf(rho);
    float c = __cosf(rho);            // c >= 0.9397
    float cb = 2.f * c * c - 1.f;     // cos(2*rho) >= 0.766
    float sb = 2.f * s * c;           // sin(2*rho)
    float rcb = 1.f / cb;

    float ic  = 0.5f * Wc * (1.f - c) - tx;
    float id_ = -sb * c * rcb;        // |id_| <= 0.789
    float ie  = c * rcb;              // 1.0 <= ie <= 1.227
    float P   = 0.5f * (Wc * c - Wc + 2.f * tx);
    float Q   = 0.5f * (Hc * c - Wc * cb + 2.f * ty * cb - Wc * sb + 2.f * tx * sb);
    float if_ = (sb * P - Q) * rcb;
    // sx = fmaf(c, x, ic); sy = fmaf(id_, x, fmaf(ie, y, if_))

    // ---- tile source bounds via corners (same fmaf composition as below;
    //      fma monotone per operand, c>0, ie>0 -> corners bound the tile) ----
    float X0f = (float)X0, X1f = (float)(X0 + 63);
    float Y0f = (float)Y0, Y1f = (float)(Y0 + 31);
    float sxlo = fmaf(c, X0f, ic);
    int lxmin = clampi((int)floorf(sxlo), 0, IMW - 2);
    int axlo = lxmin & ~3;            // 16B-aligned staging origin

    float g0 = fmaf(ie, Y0f, if_);
    float g1 = fmaf(ie, Y1f, if_);    // g1 >= g0
    float syA = fmaf(id_, X0f, g0), syB = fmaf(id_, X1f, g0);
    float syC = fmaf(id_, X0f, g1), syD = fmaf(id_, X1f, g1);
    float symin = fminf(fminf(syA, syB), fminf(syC, syD));
    float symax = fmaxf(fmaxf(syA, syB), fmaxf(syC, syD));
    int rlo = clampi((int)floorf(symin), 0, IMH - 1);
    int rhi = clampi((int)floorf(symax) + 1, 0, IMH - 1);
    int NR = rhi - rlo + 1;           // <= 91 by construction
    int nq = NR * XW4;                // float4 slots to stage (<= 1547)

    // ---- per-thread x taps (channel- and row-invariant) ----
    float fx = (float)(X0 + dx);
    float sx = fmaf(c, fx, ic);
    float x0f = floorf(sx);
    int x0 = (int)x0f;
    float wx = sx - x0f;
    int lx = clampi(x0, 0, IMW - 2);  // (lx,lx+1) provably inside staged cols
    float wl = (x0 == lx) ? (1.f - wx) : ((x0 == lx - 1) ? wx : 0.f);
    float wh = (x0 == lx) ? wx : ((x0 == lx + 1) ? (1.f - wx) : 0.f);
    int px = lx - axlo;               // 0..66

    // ---- per-thread y taps: 8 rows, precomputed, reused per channel ----
    int   a0[8], a1[8];
    float wy0[8], wy1[8];
    #pragma unroll
    for (int k = 0; k < 8; ++k) {
        float fy = (float)(Y0 + qy + 4 * k);
        float sy = fmaf(id_, fx, fmaf(ie, fy, if_));
        float y0f = floorf(sy);
        int y0 = (int)y0f;
        int y1 = y0 + 1;
        float wy = sy - y0f;
        wy0[k] = ((y0 >= 0) & (y0 < IMH)) ? (1.f - wy) : 0.f;
        wy1[k] = ((y1 >= 0) & (y1 < IMH)) ? wy : 0.f;
        // clamp is monotone -> staged window [rlo,rhi] contains both rows
        a0[k] = (clampi(y0, 0, IMH - 1) - rlo) * XW + px;
        a1[k] = (clampi(y1, 0, IMH - 1) - rlo) * XW + px;
    }

    const float* ibase = img + (size_t)b * CH * HW;
    float* obase = out + (size_t)b * CH * HW + (Y0 + qy) * IMW + X0 + dx;

    float4 pre[NPF];   // fully-unrolled static indexing -> stays in VGPRs

    // prefetch channel ch into pre[]
    #define PREFETCH(ch_) {                                                   \
        const float* cbase = ibase + (ch_) * HW;                              \
        _Pragma("unroll")                                                     \
        for (int it = 0; it < NPF; ++it) {                                    \
            int e = tid + it * 256;                                           \
            if (e < nq) {                                                     \
                unsigned row = (unsigned)e / XW4;                             \
                int q = e - (int)row * XW4;                                   \
                int gq = min(axlo + 4 * q, IMW - 4); /* 4-aligned: no overlap \
                      with sampled px range (axlo+4q<=252 whenever sampled) */\
                pre[it] = *(const float4*)(cbase + (rlo + (int)row) * IMW + gq);\
            }                                                                 \
        }                                                                     \
    }

    #define WRITE_STAGE(buf_) {                                               \
        _Pragma("unroll")                                                     \
        for (int it = 0; it < NPF; ++it) {                                    \
            int e = tid + it * 256;                                           \
            if (e < nq) {                                                     \
                unsigned row = (unsigned)e / XW4;                             \
                int q = e - (int)row * XW4;                                   \
                *((float4*)&(buf_)[row * XW + 4 * q]) = pre[it];              \
            }                                                                 \
        }                                                                     \
    }

    #define SAMPLE(ch_, buf_) {                                               \
        _Pragma("unroll")                                                     \
        for (int k = 0; k < 8; ++k) {                                         \
            float l00 = (buf_)[a0[k]], l01 = (buf_)[a0[k] + 1];               \
            float l10 = (buf_)[a1[k]], l11 = (buf_)[a1[k] + 1];               \
            float v = (l00 * wl + l01 * wh) * wy0[k]                          \
                    + (l10 * wl + l11 * wh) * wy1[k];                         \
            __builtin_nontemporal_store(v, obase + (ch_) * HW + 4 * k * IMW); \
        }                                                                     \
    }

    // ---- 3-barrier double-buffered channel pipeline ----
    PREFETCH(0);
    WRITE_STAGE(bufA);
    PREFETCH(1);            // in flight across the barrier region
    __syncthreads();        // A staged (barrier drains vmcnt -> pre[1] ready)
    SAMPLE(0, bufA);
    WRITE_STAGE(bufB);
    PREFETCH(2);
    __syncthreads();        // B staged; everyone done reading A
    SAMPLE(1, bufB);
    WRITE_STAGE(bufA);
    __syncthreads();        // A staged
    SAMPLE(2, bufA);

    #undef PREFETCH
    #undef WRITE_STAGE
    #undef SAMPLE
}

extern "C" void kernel_launch(void* const* d_in, const int* in_sizes, int n_in,
                              void* d_out, int out_size, void* d_ws, size_t ws_size,
                              hipStream_t stream) {
    const float* img = (const float*)d_in[0];
    const float* rnd = (const float*)d_in[1];
    float* out = (float*)d_out;
    (void)d_ws; (void)ws_size;

    hipLaunchKernelGGL(TCR_52536039964687_warp, dim3(BATCH * 32), dim3(256), 0, stream,
                       img, rnd, out);
}